// Round 6
// baseline (334.954 us; speedup 1.0000x reference)
//
#include <hip/hip_runtime.h>

#define CCH 16
#define DD 64
#define HH 96
#define WW 96
#define HW (HH*WW)
#define DHW (DD*HH*WW)   // 589824
#define CH4 (DHW/4)      // 147456
#define NTH 256          // 16 lh x 16 lc, 2 w-sites per thread (32-w tile)
#define DCH 8            // depth outputs per block
#define NBY (DD/DCH)     // 8 depth chunks
#define NWT 3            // w tiles (3 x 32 = 96)
#define NHT 8            // h tiles (8 x 12 = 96)
#define NPART (NWT*NHT*NBY)   // 192 partials per channel
#define KTR 1.08f        // 27 * k_harris (S unscaled by 1/27; ranking-invariant)
#define INV27C (1.f/19683.f)

typedef float v2f __attribute__((ext_vector_type(2)));

// DPP row16 shifts: thread layout is lh-fast (lh = tid & 15), so a DPP row of
// 16 lanes == one h-column; bound_ctrl=true zero-fills at row ends (filled
// sites only feed masked-out outputs). Harris is invariant to an up/down swap.
__device__ __forceinline__ float dpp_up(float v) {
    return __int_as_float(__builtin_amdgcn_update_dpp(
        0, __float_as_int(v), 0x111 /*row_shr:1*/, 0xF, 0xF, true));
}
__device__ __forceinline__ float dpp_dn(float v) {
    return __int_as_float(__builtin_amdgcn_update_dpp(
        0, __float_as_int(v), 0x101 /*row_shl:1*/, 0xF, 0xF, true));
}

// R17: same proven spill-free body (R15: full unroll + per-slice VMEM fences,
// 40 VGPR), restructured for the 54% utilization cap. R12 vs R15 showed
// VALU-issue time is INVARIANT (~30.7 us) -> dur is set by the utilization
// cap. Two candidate causes, both fixed here in one restructure:
//  (a) L1I: 18-slice unrolled body ~36 KB > 32 KB I$. Now 10 slices ~20 KB.
//  (b) occupancy: 768-thr blocks gave 24/32 waves/CU. Now 256-thr blocks,
//      grid 3072 -> 8 blocks/CU x 4 waves = 32/32 waves (100%).
// Legal because there is no inter-thread dependency along w (halo gradients
// are self-computed from own loads); only DPP's 16-lane h-rows constrain
// layout. Cost: depth-halo overhead 10/8 vs 18/16 (~+11% issue time).
__global__ __launch_bounds__(NTH, 8)
void harris_sum_kernel(const float* __restrict__ x, float* __restrict__ pp) {
    __shared__ float red[NTH/64];

    const int tid = threadIdx.x;
    const int lh = tid & 15, lc = tid >> 4;   // lc 0..15
    const int c  = blockIdx.z;
    const int wt = blockIdx.x % NWT;          // w tile 0..2
    const int ht = blockIdx.x / NWT;          // h tile 0..7
    const int H0 = ht * 12;
    const int W0 = wt * 32;
    const int o0 = blockIdx.y * DCH;
    const int gh = H0 + lh - 2;
    const int gw = W0 + (lc << 1);            // first own w site
    const bool rowok = ((unsigned)gh < HH);
    const bool lok = (gw > 0);                // site w-1 exists
    const bool rok = (gw + 2 < WW);           // site w+2 exists
    const float mask  = rowok ? 1.f : 0.f;           // gradient row mask
    const float maskl = (rowok && lok) ? 1.f : 0.f;  // halo-site masks
    const float maskr = (rowok && rok) ? 1.f : 0.f;
    const float em = (lh >= 2 && lh <= 13) ? 1.f : 0.f;

    const int ghc   = min(max(gh, 0), HH - 1);       // row-clamped: always-valid addr
    const int woffc = ghc * WW + gw;
    const int woffl = lok ? woffc - 2 : woffc;       // w-halo offsets, edge-clamped
    const int woffr = rok ? woffc + 2 : woffc;       // (needs w+3 valid; clamp at edge)
    const float* xc = x + (size_t)c * DHW;

    // x window: slices e-1(p), e(m), e+1(n), in-flight (f); L/C/R = x[w-2..w+3]
    v2f Lp,Cp,Rp, Lm,Cm,Rm, Ln,Cn,Rn;

    auto loadslice = [&](int e, v2f& L, v2f& C, v2f& R) {
        const int ec = min(max(e, 0), DD - 1);       // depth-clamped (uniform SALU)
        const float* sp = xc + (size_t)(ec * HW);
        C = *(const v2f*)(sp + woffc);
        L = *(const v2f*)(sp + woffl);
        R = *(const v2f*)(sp + woffr);
        if (e != ec) {                               // uniform branch (edge chunks only)
            L = (v2f){0.f,0.f}; C = (v2f){0.f,0.f}; R = (v2f){0.f,0.f};
        }
        // row/edge zero-pad (broadcast-scalar pk muls)
        L *= (v2f){maskl, maskl};
        C *= (v2f){mask,  mask};
        R *= (v2f){maskr, maskr};
    };

    loadslice(o0 - 2, Lp, Cp, Rp);
    loadslice(o0 - 1, Lm, Cm, Rm);
    loadslice(o0,     Ln, Cn, Rn);

    v2f s2m1[6], s2m2[6];
    #pragma unroll
    for (int f = 0; f < 6; ++f) {
        s2m1[f] = (v2f){0.f,0.f};
        s2m2[f] = (v2f){0.f,0.f};
    }
    v2f hv = {0.f, 0.f};

    #pragma unroll
    for (int k = 0; k < DCH + 2; ++k) {       // 10 slices -> 8 output slices
        const int e = o0 - 1 + k;

        // prefetch slice e+2 (consumed next iteration; vmcnt(3) wait pattern)
        v2f Lf = {0.f,0.f}, Cf = {0.f,0.f}, Rf = {0.f,0.f};
        if (k < DCH + 1) loadslice(e + 2, Lf, Cf, Rf);

        // depth window (pk)
        const v2f AL = (Lp + Lm) + Ln;
        const v2f AC = (Cp + Cm) + Cn;
        const v2f AR = (Rp + Rm) + Rn;
        const v2f DL = Ln - Lp;
        const v2f DC = Cn - Cp;
        const v2f DR = Rn - Rp;

        // w-convs at sites l,0,1,r
        const v2f SxA = AC - AL;              // {Sxl, Sx0}  pk
        const v2f SxB = AR - AC;              // {Sx1, Sxr}  pk
        const float Txl = fmaf(2.f, AL.y, AL.x + AC.x);
        const float Tx0 = fmaf(2.f, AC.x, AL.y + AC.y);
        const float Tx1 = fmaf(2.f, AC.y, AC.x + AR.x);
        const float Txr = fmaf(2.f, AR.x, AC.y + AR.y);
        const float p01 = DL.y + DC.x, p23 = DC.y + DR.x;
        const float Tdl = DL.x + p01,  Td0 = p01 + DC.y;
        const float Td1 = DC.x + p23,  Tdr = p23 + DR.y;

        // h-convs via DPP; paired-add form -> folds into v_add_f32_dpp
        #define HX(S)  ((dpp_up(S) + (S)) + (dpp_dn(S) + (S)))
        #define HY(T)  (dpp_dn(T) - dpp_up(T))
        #define HZ(T)  ((dpp_up(T) + (T)) + dpp_dn(T))
        v2f gxA = {HX(SxA.x), HX(SxA.y)};  gxA *= (v2f){maskl, mask};   // {glx, gx0}
        v2f gxB = {HX(SxB.x), HX(SxB.y)};  gxB *= (v2f){mask, maskr};   // {gx1, grx}
        v2f gyA = {HY(Txl),   HY(Tx0)};    gyA *= (v2f){maskl, mask};
        v2f gyB = {HY(Tx1),   HY(Txr)};    gyB *= (v2f){mask, maskr};
        v2f gzA = {HZ(Tdl),   HZ(Td0)};    gzA *= (v2f){maskl, mask};
        v2f gzB = {HZ(Td1),   HZ(Tdr)};    gzB *= (v2f){mask, maskr};

        // products: own pair {g0,g1} packed; halo pair {gl,gr} packed
        const v2f gx0v = {gxA.y, gxB.x}, gy0v = {gyA.y, gyB.x}, gz0v = {gzA.y, gzB.x};
        const v2f gxh  = {gxA.x, gxB.y}, gyh  = {gyA.x, gyB.y}, gzh  = {gzA.x, gzB.y};
        const v2f Pxx = gx0v*gx0v, Pyy = gy0v*gy0v, Pzz = gz0v*gz0v;
        const v2f Pxy = gx0v*gy0v, Pxz = gx0v*gz0v, Pyz = gy0v*gz0v;
        const v2f Phxx = gxh*gxh, Phyy = gyh*gyh, Phzz = gzh*gzh;
        const v2f Phxy = gxh*gyh, Phxz = gxh*gzh, Phyz = gyh*gzh;

        // w [1,1,1] on products + h [1,1,1] via fused-DPP adds
        v2f s2c[6];
        #define FIELD(f, Pv, Ph)                                       \
        {   const float s_ = (Pv).x + (Pv).y;                          \
            const v2f Rv = (Ph) + (v2f){s_, s_};                       \
            s2c[f].x = HZ(Rv.x);                                       \
            s2c[f].y = HZ(Rv.y); }
        FIELD(0, Pxx, Phxx)
        FIELD(1, Pyy, Phyy)
        FIELD(2, Pzz, Phzz)
        FIELD(3, Pxy, Phxy)
        FIELD(4, Pxz, Phxz)
        FIELD(5, Pyz, Phyz)
        #undef FIELD
        #undef HX
        #undef HY
        #undef HZ

        if (k >= 2) {   // compile-time under full unroll; emit slice o = e-1
            const v2f sxx = (s2m2[0] + s2m1[0]) + s2c[0];
            const v2f syy = (s2m2[1] + s2m1[1]) + s2c[1];
            const v2f szz = (s2m2[2] + s2m1[2]) + s2c[2];
            const v2f sxy = (s2m2[3] + s2m1[3]) + s2c[3];
            const v2f sxz = (s2m2[4] + s2m1[4]) + s2c[4];
            const v2f syz = (s2m2[5] + s2m1[5]) + s2c[5];
            const v2f det = sxx*(syy*szz - syz*syz)
                          - sxy*(sxy*szz - syz*sxz)
                          + sxz*(sxy*syz - syy*sxz);
            const v2f tr = (sxx + syy) + szz;
            hv += det - KTR*(tr*tr);   // emit-row mask deferred to the end
        }
        #pragma unroll
        for (int f = 0; f < 6; ++f) { s2m2[f] = s2m1[f]; s2m1[f] = s2c[f]; }
        Lp = Lm; Cp = Cm; Rp = Rm;
        Lm = Ln; Cm = Cn; Rm = Rn;
        Ln = Lf; Cn = Cf; Rn = Rf;

        // fence: ALU(0x1)|VALU(0x2)|SALU(0x4) may cross; VMEM/DS pinned to
        // their slice -> no cross-slice load hoisting (the R13/R14 spill cause)
        __builtin_amdgcn_sched_barrier(0x7);
    }

    // non-emitted rows (lh<2 || lh>13) computed finite garbage; zero it here
    float hs = (hv.x + hv.y) * em;
    // block reduce -> per-block partial slot (no atomics, no ws init needed)
    #pragma unroll
    for (int o = 32; o > 0; o >>= 1) hs += __shfl_down(hs, o, 64);
    if ((tid & 63) == 0) red[tid >> 6] = hs;
    __syncthreads();
    if (tid == 0) {
        float s = 0.f;
        #pragma unroll
        for (int i = 0; i < NTH/64; ++i) s += red[i];
        pp[c * NPART + blockIdx.y * (NWT*NHT) + blockIdx.x] = s * INV27C;
    }
}

// Fused select+gather: every block recomputes the top-8 selection from pp
// (16x192 L2-hit loads + parallel rank -- cheaper than a separate kernel
// launch), then streams its copy tile. Summation order and rank tiebreak are
// fixed -> same selection in every block, deterministic.
__global__ __launch_bounds__(256)
void gather_topk_kernel(const float* __restrict__ x, const float* __restrict__ pp,
                        float4* __restrict__ out) {
    __shared__ float pv[CCH];
    __shared__ int sidx[8];
    const int tid = threadIdx.x;
    if (tid < CCH) {
        float s = 0.f;
        for (int j = 0; j < NPART; ++j) s += pp[tid * NPART + j];
        pv[tid] = s;   // fixed order -> deterministic across blocks
    }
    __syncthreads();
    if (tid < CCH) {
        const float v = pv[tid];
        int r = 0;
        #pragma unroll
        for (int i = 0; i < CCH; ++i) {
            const float u = pv[i];
            r += (u > v) || (u == v && i < tid);
        }
        if (r < 8) sidx[r] = tid;
    }
    __syncthreads();
    const int j = blockIdx.y;                        // 0..7
    const int cidx = sidx[j];                        // uniform
    const float4* src = (const float4*)(x + (size_t)cidx * DHW);
    float4* dst = out + (size_t)j * CH4;
    const int base = blockIdx.x * 1024 + tid;        // 144*1024 == CH4 exact
    #pragma unroll
    for (int t = 0; t < 4; ++t)
        dst[base + t * 256] = src[base + t * 256];
}

extern "C" void kernel_launch(void* const* d_in, const int* in_sizes, int n_in,
                              void* d_out, int out_size, void* d_ws, size_t ws_size,
                              hipStream_t stream) {
    const float* x = (const float*)d_in[0];
    float4* out = reinterpret_cast<float4*>(d_out);
    float* pp = (float*)d_ws;                        // 16*192 partials (12 KB)

    dim3 g1(NWT * NHT, NBY, CCH);                    // (24, 8, 16) = 3072 blocks
    harris_sum_kernel<<<g1, NTH, 0, stream>>>(x, pp);

    dim3 g2(CH4 / 1024, 8, 1);                       // (144, 8)
    gather_topk_kernel<<<g2, 256, 0, stream>>>(x, pp, out);
}

// Round 7
// 143.837 us; speedup vs baseline: 2.3287x; 2.3287x over previous
//
#include <hip/hip_runtime.h>

#define CCH 16
#define DD 64
#define HH 96
#define WW 96
#define HW (HH*WW)
#define DHW (DD*HH*WW)   // 589824
#define CH4 (DHW/4)      // 147456
#define NTH 384          // 16 lh x 24 lc, 2 w-sites per thread (48-w tile)
#define DCH 8            // depth outputs per block
#define NBY (DD/DCH)     // 8 depth chunks
#define NWT 2            // w tiles (2 x 48 = 96)
#define NHT 8            // h tiles (8 x 12 = 96)
#define NPART (NWT*NHT*NBY)   // 128 partials per channel
#define KTR 1.08f        // 27 * k_harris (S unscaled by 1/27; ranking-invariant)
#define INV27C (1.f/19683.f)

typedef float v2f __attribute__((ext_vector_type(2)));

// DPP row16 shifts: thread layout is lh-fast (lh = tid & 15), so a DPP row of
// 16 lanes == one h-column; bound_ctrl=true zero-fills at row ends (filled
// sites only feed masked-out outputs). Harris is invariant to an up/down swap.
__device__ __forceinline__ float dpp_up(float v) {
    return __int_as_float(__builtin_amdgcn_update_dpp(
        0, __float_as_int(v), 0x111 /*row_shr:1*/, 0xF, 0xF, true));
}
__device__ __forceinline__ float dpp_dn(float v) {
    return __int_as_float(__builtin_amdgcn_update_dpp(
        0, __float_as_int(v), 0x101 /*row_shl:1*/, 0xF, 0xF, true));
}

// R18: R15's EXACT body (full unroll + per-slice VMEM fences), geometry only:
//  - 384-thread blocks (6 waves): 5 blocks/CU = 30/32 wave slots (R15's
//    768-thr blocks capped at 2 blocks = 24/32, grid exactly 2/CU -> no tail
//    smoothing; measured occupancy only 57%).
//  - launch_bounds(384,6): SAME 85-VGPR budget as R15's proven codegen.
//    R17's (256,8)=64-VGPR budget collapsed the allocator (spill 543 MB,
//    VGPR 32): this body needs ~85 transient budget even though the final
//    allocation is 40.
//  - DCH=8 -> grid 2048 = 8 blocks/CU available: refill smoothing.
//    Cost: depth-halo 10/8 vs 18/16 (+12.5% issue work, +10% FETCH).
//  - 10-slice body ~20 KB also fits 32 KB L1I (accepted confound with the
//    occupancy fix).
__global__ __launch_bounds__(NTH, 6)
void harris_sum_kernel(const float* __restrict__ x, float* __restrict__ pp) {
    __shared__ float red[NTH/64];

    const int tid = threadIdx.x;
    const int lh = tid & 15, lc = tid >> 4;   // lc 0..23
    const int c  = blockIdx.z;
    const int wt = blockIdx.x % NWT;          // w tile 0..1
    const int ht = blockIdx.x / NWT;          // h tile 0..7
    const int H0 = ht * 12;
    const int W0 = wt * 48;
    const int o0 = blockIdx.y * DCH;
    const int gh = H0 + lh - 2;
    const int gw = W0 + (lc << 1);            // first own w site
    const bool rowok = ((unsigned)gh < HH);
    const bool lok = (gw > 0);                // site w-1 exists
    const bool rok = (gw + 2 < WW);           // site w+2 exists
    const float mask  = rowok ? 1.f : 0.f;           // gradient row mask
    const float maskl = (rowok && lok) ? 1.f : 0.f;  // halo-site masks
    const float maskr = (rowok && rok) ? 1.f : 0.f;
    const float em = (lh >= 2 && lh <= 13) ? 1.f : 0.f;

    const int ghc   = min(max(gh, 0), HH - 1);       // row-clamped: always-valid addr
    const int woffc = ghc * WW + gw;
    const int woffl = lok ? woffc - 2 : woffc;       // w-halo offsets, edge-clamped
    const int woffr = rok ? woffc + 2 : woffc;
    const float* xc = x + (size_t)c * DHW;

    // x window: slices e-1(p), e(m), e+1(n), in-flight (f); L/C/R = x[w-2..w+3]
    v2f Lp,Cp,Rp, Lm,Cm,Rm, Ln,Cn,Rn;

    auto loadslice = [&](int e, v2f& L, v2f& C, v2f& R) {
        const int ec = min(max(e, 0), DD - 1);       // depth-clamped (uniform SALU)
        const float* sp = xc + (size_t)(ec * HW);
        C = *(const v2f*)(sp + woffc);
        L = *(const v2f*)(sp + woffl);
        R = *(const v2f*)(sp + woffr);
        if (e != ec) {                               // uniform branch (edge chunks only)
            L = (v2f){0.f,0.f}; C = (v2f){0.f,0.f}; R = (v2f){0.f,0.f};
        }
        // row/edge zero-pad (broadcast-scalar pk muls)
        L *= (v2f){maskl, maskl};
        C *= (v2f){mask,  mask};
        R *= (v2f){maskr, maskr};
    };

    loadslice(o0 - 2, Lp, Cp, Rp);
    loadslice(o0 - 1, Lm, Cm, Rm);
    loadslice(o0,     Ln, Cn, Rn);

    v2f s2m1[6], s2m2[6];
    #pragma unroll
    for (int f = 0; f < 6; ++f) {
        s2m1[f] = (v2f){0.f,0.f};
        s2m2[f] = (v2f){0.f,0.f};
    }
    v2f hv = {0.f, 0.f};

    #pragma unroll
    for (int k = 0; k < DCH + 2; ++k) {       // 10 slices -> 8 output slices
        const int e = o0 - 1 + k;

        // prefetch slice e+2 (consumed next iteration; vmcnt(3) wait pattern)
        v2f Lf = {0.f,0.f}, Cf = {0.f,0.f}, Rf = {0.f,0.f};
        if (k < DCH + 1) loadslice(e + 2, Lf, Cf, Rf);

        // depth window (pk)
        const v2f AL = (Lp + Lm) + Ln;
        const v2f AC = (Cp + Cm) + Cn;
        const v2f AR = (Rp + Rm) + Rn;
        const v2f DL = Ln - Lp;
        const v2f DC = Cn - Cp;
        const v2f DR = Rn - Rp;

        // w-convs at sites l,0,1,r
        const v2f SxA = AC - AL;              // {Sxl, Sx0}  pk
        const v2f SxB = AR - AC;              // {Sx1, Sxr}  pk
        const float Txl = fmaf(2.f, AL.y, AL.x + AC.x);
        const float Tx0 = fmaf(2.f, AC.x, AL.y + AC.y);
        const float Tx1 = fmaf(2.f, AC.y, AC.x + AR.x);
        const float Txr = fmaf(2.f, AR.x, AC.y + AR.y);
        const float p01 = DL.y + DC.x, p23 = DC.y + DR.x;
        const float Tdl = DL.x + p01,  Td0 = p01 + DC.y;
        const float Td1 = DC.x + p23,  Tdr = p23 + DR.y;

        // h-convs via DPP; paired-add form -> folds into v_add_f32_dpp
        #define HX(S)  ((dpp_up(S) + (S)) + (dpp_dn(S) + (S)))
        #define HY(T)  (dpp_dn(T) - dpp_up(T))
        #define HZ(T)  ((dpp_up(T) + (T)) + dpp_dn(T))
        v2f gxA = {HX(SxA.x), HX(SxA.y)};  gxA *= (v2f){maskl, mask};   // {glx, gx0}
        v2f gxB = {HX(SxB.x), HX(SxB.y)};  gxB *= (v2f){mask, maskr};   // {gx1, grx}
        v2f gyA = {HY(Txl),   HY(Tx0)};    gyA *= (v2f){maskl, mask};
        v2f gyB = {HY(Tx1),   HY(Txr)};    gyB *= (v2f){mask, maskr};
        v2f gzA = {HZ(Tdl),   HZ(Td0)};    gzA *= (v2f){maskl, mask};
        v2f gzB = {HZ(Td1),   HZ(Tdr)};    gzB *= (v2f){mask, maskr};

        // products: own pair {g0,g1} packed; halo pair {gl,gr} packed
        const v2f gx0v = {gxA.y, gxB.x}, gy0v = {gyA.y, gyB.x}, gz0v = {gzA.y, gzB.x};
        const v2f gxh  = {gxA.x, gxB.y}, gyh  = {gyA.x, gyB.y}, gzh  = {gzA.x, gzB.y};
        const v2f Pxx = gx0v*gx0v, Pyy = gy0v*gy0v, Pzz = gz0v*gz0v;
        const v2f Pxy = gx0v*gy0v, Pxz = gx0v*gz0v, Pyz = gy0v*gz0v;
        const v2f Phxx = gxh*gxh, Phyy = gyh*gyh, Phzz = gzh*gzh;
        const v2f Phxy = gxh*gyh, Phxz = gxh*gzh, Phyz = gyh*gzh;

        // w [1,1,1] on products + h [1,1,1] via fused-DPP adds
        v2f s2c[6];
        #define FIELD(f, Pv, Ph)                                       \
        {   const float s_ = (Pv).x + (Pv).y;                          \
            const v2f Rv = (Ph) + (v2f){s_, s_};                       \
            s2c[f].x = HZ(Rv.x);                                       \
            s2c[f].y = HZ(Rv.y); }
        FIELD(0, Pxx, Phxx)
        FIELD(1, Pyy, Phyy)
        FIELD(2, Pzz, Phzz)
        FIELD(3, Pxy, Phxy)
        FIELD(4, Pxz, Phxz)
        FIELD(5, Pyz, Phyz)
        #undef FIELD
        #undef HX
        #undef HY
        #undef HZ

        if (k >= 2) {   // compile-time under full unroll; emit slice o = e-1
            const v2f sxx = (s2m2[0] + s2m1[0]) + s2c[0];
            const v2f syy = (s2m2[1] + s2m1[1]) + s2c[1];
            const v2f szz = (s2m2[2] + s2m1[2]) + s2c[2];
            const v2f sxy = (s2m2[3] + s2m1[3]) + s2c[3];
            const v2f sxz = (s2m2[4] + s2m1[4]) + s2c[4];
            const v2f syz = (s2m2[5] + s2m1[5]) + s2c[5];
            const v2f det = sxx*(syy*szz - syz*syz)
                          - sxy*(sxy*szz - syz*sxz)
                          + sxz*(sxy*syz - syy*sxz);
            const v2f tr = (sxx + syy) + szz;
            hv += det - KTR*(tr*tr);   // emit-row mask deferred to the end
        }
        #pragma unroll
        for (int f = 0; f < 6; ++f) { s2m2[f] = s2m1[f]; s2m1[f] = s2c[f]; }
        Lp = Lm; Cp = Cm; Rp = Rm;
        Lm = Ln; Cm = Cn; Rm = Rn;
        Ln = Lf; Cn = Cf; Rn = Rf;

        // fence: ALU(0x1)|VALU(0x2)|SALU(0x4) may cross; VMEM/DS pinned to
        // their slice -> no cross-slice load hoisting (the R13/R14 spill cause)
        __builtin_amdgcn_sched_barrier(0x7);
    }

    // non-emitted rows (lh<2 || lh>13) computed finite garbage; zero it here
    float hs = (hv.x + hv.y) * em;
    // block reduce -> per-block partial slot (no atomics, no ws init needed)
    #pragma unroll
    for (int o = 32; o > 0; o >>= 1) hs += __shfl_down(hs, o, 64);
    if ((tid & 63) == 0) red[tid >> 6] = hs;
    __syncthreads();
    if (tid == 0) {
        float s = 0.f;
        #pragma unroll
        for (int i = 0; i < NTH/64; ++i) s += red[i];
        pp[c * NPART + blockIdx.y * (NWT*NHT) + blockIdx.x] = s * INV27C;
    }
}

// Fused select+gather: every block recomputes the top-8 selection from pp
// (16x128 L2-hit loads + parallel rank -- cheaper than a separate kernel
// launch), then streams its copy tile. Summation order and rank tiebreak are
// fixed -> same selection in every block, deterministic.
__global__ __launch_bounds__(256)
void gather_topk_kernel(const float* __restrict__ x, const float* __restrict__ pp,
                        float4* __restrict__ out) {
    __shared__ float pv[CCH];
    __shared__ int sidx[8];
    const int tid = threadIdx.x;
    if (tid < CCH) {
        float s = 0.f;
        for (int j = 0; j < NPART; ++j) s += pp[tid * NPART + j];
        pv[tid] = s;   // fixed order -> deterministic across blocks
    }
    __syncthreads();
    if (tid < CCH) {
        const float v = pv[tid];
        int r = 0;
        #pragma unroll
        for (int i = 0; i < CCH; ++i) {
            const float u = pv[i];
            r += (u > v) || (u == v && i < tid);
        }
        if (r < 8) sidx[r] = tid;
    }
    __syncthreads();
    const int j = blockIdx.y;                        // 0..7
    const int cidx = sidx[j];                        // uniform
    const float4* src = (const float4*)(x + (size_t)cidx * DHW);
    float4* dst = out + (size_t)j * CH4;
    const int base = blockIdx.x * 1024 + tid;        // 144*1024 == CH4 exact
    #pragma unroll
    for (int t = 0; t < 4; ++t)
        dst[base + t * 256] = src[base + t * 256];
}

extern "C" void kernel_launch(void* const* d_in, const int* in_sizes, int n_in,
                              void* d_out, int out_size, void* d_ws, size_t ws_size,
                              hipStream_t stream) {
    const float* x = (const float*)d_in[0];
    float4* out = reinterpret_cast<float4*>(d_out);
    float* pp = (float*)d_ws;                        // 16*128 partials (8 KB)

    dim3 g1(NWT * NHT, NBY, CCH);                    // (16, 8, 16) = 2048 blocks
    harris_sum_kernel<<<g1, NTH, 0, stream>>>(x, pp);

    dim3 g2(CH4 / 1024, 8, 1);                       // (144, 8)
    gather_topk_kernel<<<g2, 256, 0, stream>>>(x, pp, out);
}